// Round 7
// baseline (198.356 us; speedup 1.0000x reference)
//
#include <hip/hip_runtime.h>
#include <hip/hip_bf16.h>

#define LN_EPS 1e-5f

typedef __attribute__((ext_vector_type(8))) short s8v;
typedef __attribute__((ext_vector_type(4))) float f32x4;

// ---------- helpers ----------
__device__ __forceinline__ float wred_sum(float v) {
#pragma unroll
  for (int o = 32; o > 0; o >>= 1) v += __shfl_xor(v, o, 64);
  return v;
}
__device__ __forceinline__ float wred_max(float v) {
#pragma unroll
  for (int o = 32; o > 0; o >>= 1) v = fmaxf(v, __shfl_xor(v, o, 64));
  return v;
}
__device__ __forceinline__ float bsum256(float v, float* s4) {
  v = wred_sum(v);
  int lane = threadIdx.x & 63, w = threadIdx.x >> 6;
  __syncthreads();
  if (lane == 0) s4[w] = v;
  __syncthreads();
  return s4[0] + s4[1] + s4[2] + s4[3];
}
__device__ __forceinline__ float bf2f(unsigned short u) {
  union { unsigned int i; float f; } c;
  c.i = ((unsigned int)u) << 16;
  return c.f;
}
__device__ __forceinline__ unsigned short f2bf(float f) {
  __hip_bfloat16 h = (__hip_bfloat16)f;
  return *(unsigned short*)&h;
}
__device__ __forceinline__ void async_cp16(const __hip_bfloat16* g, __hip_bfloat16* l) {
  __builtin_amdgcn_global_load_lds(
      (const __attribute__((address_space(1))) unsigned int*)g,
      (__attribute__((address_space(3))) unsigned int*)l, 16, 0, 0);
}

// ---------- fused prep: ln(wpe)->p0b, ln(wte[tokens])->e, W1^T, zero accs ----------
__global__ void prep_k(const float* __restrict__ wpe, const float* __restrict__ wte,
                       const int* __restrict__ tokens,
                       const float* __restrict__ g_p, const float* __restrict__ g_e,
                       const float* __restrict__ ff_w1,
                       unsigned short* __restrict__ p0b, unsigned short* __restrict__ e,
                       unsigned short* __restrict__ w1T, float* __restrict__ zeros) {
  __shared__ float lds[64][65];
  int bx = blockIdx.x, t = threadIdx.x;
  int w = t >> 6, lane = t & 63;

  if (bx < 5120) {  // layernorm roles, wave per row
    int row;
    const float* g;
    const float4* src;
    if (bx < 1024) {           // p0 = LN(wpe[:4096], g_p)
      row = bx * 4 + w;
      src = (const float4*)(wpe + (size_t)row * 256);
      g = g_p;
    } else {                   // e = LN(wte[tokens], g_e)
      row = (bx - 1024) * 4 + w;
      int tok = tokens[row];
      src = (const float4*)(wte + (size_t)tok * 256);
      g = g_e;
    }
    float4 v = src[lane];
    float mean = wred_sum(v.x + v.y + v.z + v.w) * (1.f / 256.f);
    float4 d = {v.x - mean, v.y - mean, v.z - mean, v.w - mean};
    float var = wred_sum(d.x * d.x + d.y * d.y + d.z * d.z + d.w * d.w) * (1.f / 256.f);
    float r = rsqrtf(var + LN_EPS);
    float4 gv = ((const float4*)g)[lane];
    ushort4 ob = {f2bf(d.x * r * gv.x), f2bf(d.y * r * gv.y),
                  f2bf(d.z * r * gv.z), f2bf(d.w * r * gv.w)};
    if (bx < 1024) ((ushort4*)(p0b + (size_t)row * 256))[lane] = ob;
    else           ((ushort4*)(e   + (size_t)row * 256))[lane] = ob;
    return;
  }
  if (bx < 5184) {  // transpose-cast W1 (256x1024) -> w1T (1024x256)
    int i = bx - 5120;
    int bxx = i & 3, byy = i >> 2;   // 4 x 16 tiles of 64x64
    int x = t & 63, y4 = t >> 6;
    int r0 = bxx * 64, c0 = byy * 64;
#pragma unroll
    for (int k = 0; k < 16; ++k) {
      int r = y4 * 16 + k;
      lds[r][x] = ff_w1[(size_t)(r0 + r) * 1024 + c0 + x];
    }
    __syncthreads();
#pragma unroll
    for (int k = 0; k < 16; ++k) {
      int a = y4 * 16 + k;
      w1T[(size_t)(c0 + a) * 256 + r0 + x] = f2bf(lds[x][a]);
    }
    return;
  }
  // bx == 5184: zero accumulators (ctx 6144 + qall 1536 + xacc 1024 + plast 256)
  for (int i = t; i < 8960; i += 256) zeros[i] = 0.f;
}

// ---------- MFMA GEMM: C(MxN) = A(MxK) @ BT(NxK), 64x64 tile, BK=64 ----------
// mode 1: exact gelu epilogue. async global->LDS, XOR-swizzled chunks.
template <int TM>
__global__ __launch_bounds__(256, 4) void mfma_gemm(
    const __hip_bfloat16* __restrict__ A, const __hip_bfloat16* __restrict__ BT,
    __hip_bfloat16* __restrict__ Cout, int M, int N, int K, int mode) {
  constexpr int BM = TM * 32;
  __shared__ __hip_bfloat16 As[BM * 64];
  __shared__ __hip_bfloat16 Bs[64 * 64];
  const int t = threadIdx.x;
  const int lane = t & 63, wave = t >> 6;
  const int wr = wave >> 1, wc = wave & 1;
  const int fr = lane & 15, quad = lane >> 4;
  const int m0 = blockIdx.x * BM, n0 = blockIdx.y * 64;

  f32x4 acc[TM][2];
#pragma unroll
  for (int i = 0; i < TM; ++i)
#pragma unroll
    for (int j = 0; j < 2; ++j) acc[i][j] = (f32x4){0.f, 0.f, 0.f, 0.f};

  for (int k0 = 0; k0 < K; k0 += 64) {
    __syncthreads();
#pragma unroll
    for (int j = 0; j < TM; ++j) {
      int ld = wave * TM + j;
      int slot = ld * 64 + lane;
      int m = slot >> 3, c = slot & 7;
      const __hip_bfloat16* g = A + (size_t)(m0 + m) * K + k0 + ((c ^ (m & 7)) << 3);
      async_cp16(g, As + ld * 512);
    }
#pragma unroll
    for (int j = 0; j < 2; ++j) {
      int ld = wave * 2 + j;
      int slot = ld * 64 + lane;
      int n = slot >> 3, c = slot & 7;
      const __hip_bfloat16* g = BT + (size_t)(n0 + n) * K + k0 + ((c ^ (n & 7)) << 3);
      async_cp16(g, Bs + ld * 512);
    }
    __syncthreads();
#pragma unroll
    for (int h = 0; h < 2; ++h) {
      s8v af[TM], bfv[2];
#pragma unroll
      for (int i = 0; i < TM; ++i) {
        int m = wr * TM * 16 + i * 16 + fr;
        int ch = (h * 4 + quad) ^ (m & 7);
        af[i] = *(const s8v*)(As + m * 64 + ch * 8);
      }
#pragma unroll
      for (int j = 0; j < 2; ++j) {
        int n = wc * 32 + j * 16 + fr;
        int ch = (h * 4 + quad) ^ (n & 7);
        bfv[j] = *(const s8v*)(Bs + n * 64 + ch * 8);
      }
#pragma unroll
      for (int i = 0; i < TM; ++i)
#pragma unroll
        for (int j = 0; j < 2; ++j)
          acc[i][j] = __builtin_amdgcn_mfma_f32_16x16x32_bf16(af[i], bfv[j], acc[i][j], 0, 0, 0);
    }
  }

#pragma unroll
  for (int i = 0; i < TM; ++i) {
#pragma unroll
    for (int j = 0; j < 2; ++j) {
#pragma unroll
      for (int r = 0; r < 4; ++r) {
        int row = m0 + wr * TM * 16 + i * 16 + quad * 4 + r;
        int col = n0 + wc * 32 + j * 16 + fr;
        float v = acc[i][j][r];
        if (mode == 1) v = 0.5f * v * (1.f + erff(v * 0.70710678118654752f));
        Cout[(size_t)row * N + col] = (__hip_bfloat16)v;
      }
    }
  }
}

// ---------- plast[t] = p0b[4095][t] + sum_k h[4095][k]*W2[k][t]  (split-k atomics) ----------
// plast is the POST-MLP p at the last position: used for q only (not the residual!)
__global__ void plast_k(const unsigned short* __restrict__ hB,
                        const unsigned short* __restrict__ p0b,
                        const float* __restrict__ W2, float* __restrict__ plast) {
  int c = blockIdx.x, t = threadIdx.x;
  float pa = (c == 0) ? bf2f(p0b[(size_t)4095 * 256 + t]) : 0.f;
#pragma unroll
  for (int i = 0; i < 16; ++i) {
    int k = c * 16 + i;
    pa += bf2f(hB[(size_t)4095 * 1024 + k]) * W2[(size_t)k * 256 + t];  // coalesced over t
  }
  atomicAdd(&plast[t], pa);
}

// ---------- q[l][t] += sum_{d in chunk} plast[d]*Wq[l][d][t] ----------
__global__ void q_k(const float* __restrict__ plast, const float* __restrict__ Wq,
                    float* __restrict__ qall) {
  int c = blockIdx.x, l = blockIdx.y, t = threadIdx.x;
  const float* W = Wq + (size_t)l * 65536;
  float pa = 0.f;
#pragma unroll
  for (int i = 0; i < 16; ++i) {
    int d = c * 16 + i;
    pa += plast[d] * W[d * 256 + t];  // coalesced over t
  }
  atomicAdd(&qall[l * 256 + t], pa);
}

// ---------- kv[l][r] = Wk[l][r] . q[l]  (wave per row) ----------
__global__ void kv_k(const float* __restrict__ Wk, const float* __restrict__ qall,
                     float* __restrict__ kv) {
  int l = blockIdx.y;
  int w = threadIdx.x >> 6, lane = threadIdx.x & 63;
  int r = blockIdx.x * 4 + w;
  float4 wv = ((const float4*)(Wk + (size_t)l * 65536 + (size_t)r * 256))[lane];
  float4 qv = ((const float4*)(qall + l * 256))[lane];
  float dot = wred_sum(wv.x * qv.x + wv.y * qv.y + wv.z * qv.z + wv.w * qv.w);
  if (lane == 0) kv[l * 256 + r] = dot;
}

// ---------- w2kv[l][r] = W2[r] . kv[l]  (wave per row, r<1024) ----------
__global__ void w2kv_k(const float* __restrict__ W2, const float* __restrict__ kv,
                       float* __restrict__ w2kv) {
  int l = blockIdx.y;
  int w = threadIdx.x >> 6, lane = threadIdx.x & 63;
  int r = blockIdx.x * 4 + w;
  float4 wv = ((const float4*)(W2 + (size_t)r * 256))[lane];
  float4 qv = ((const float4*)(kv + l * 256))[lane];
  float dot = wred_sum(wv.x * qv.x + wv.y * qv.y + wv.z * qv.z + wv.w * qv.w);
  if (lane == 0) w2kv[l * 1024 + r] = dot;
}

// ---------- sc[l][t] = (p0b[t].kv[l] + h[t].w2kv[l]) / 16  (16 rows/block) ----------
__global__ void sc_k(const unsigned short* __restrict__ p0b, const unsigned short* __restrict__ hB,
                     const float* __restrict__ kv, const float* __restrict__ w2kv,
                     float* __restrict__ sc) {
  __shared__ float skv[6 * 256];
  __shared__ float sw2[6 * 1024];
  int t = threadIdx.x;
  for (int i = t; i < 1536; i += 256) skv[i] = kv[i];
  for (int i = t; i < 6144; i += 256) sw2[i] = w2kv[i];
  __syncthreads();
  int wave = t >> 6, lane = t & 63;
  int row0 = blockIdx.x * 16 + wave * 4;
  ushort4 hv[4][4], pv[4];
#pragma unroll
  for (int rr = 0; rr < 4; ++rr) {
    const ushort4* hrow = (const ushort4*)(hB + (size_t)(row0 + rr) * 1024);
#pragma unroll
    for (int c = 0; c < 4; ++c) hv[rr][c] = hrow[c * 64 + lane];  // elems lane*4+c*256
    pv[rr] = ((const ushort4*)(p0b + (size_t)(row0 + rr) * 256))[lane];
  }
  float acc[6][4];
#pragma unroll
  for (int l = 0; l < 6; ++l) {
    float4 kf = ((const float4*)(skv + l * 256))[lane];  // lane-contiguous: conflict-free
    float4 wf[4];
#pragma unroll
    for (int c = 0; c < 4; ++c) wf[c] = ((const float4*)(sw2 + l * 1024 + c * 256))[lane];
#pragma unroll
    for (int rr = 0; rr < 4; ++rr) {
      float a = bf2f(pv[rr].x) * kf.x + bf2f(pv[rr].y) * kf.y +
                bf2f(pv[rr].z) * kf.z + bf2f(pv[rr].w) * kf.w;
#pragma unroll
      for (int c = 0; c < 4; ++c)
        a += bf2f(hv[rr][c].x) * wf[c].x + bf2f(hv[rr][c].y) * wf[c].y +
             bf2f(hv[rr][c].z) * wf[c].z + bf2f(hv[rr][c].w) * wf[c].w;
      acc[l][rr] = a;
    }
  }
#pragma unroll
  for (int l = 0; l < 6; ++l)
#pragma unroll
    for (int rr = 0; rr < 4; ++rr) {
      float d = wred_sum(acc[l][rr]);
      if (lane == 0) sc[(size_t)l * 4096 + row0 + rr] = d * 0.0625f;
    }
}

// ---------- softmax over 4096 per layer ----------
__global__ void softmax_k(const float* __restrict__ sc, float* __restrict__ w) {
  int l = blockIdx.x, t = threadIdx.x;  // 1024 threads
  float4 v = ((const float4*)(sc + (size_t)l * 4096))[t];
  float m = fmaxf(fmaxf(v.x, v.y), fmaxf(v.z, v.w));
  m = wred_max(m);
  __shared__ float red[16];
  __shared__ float red2[16];
  int lane = t & 63, wv = t >> 6;
  if (lane == 0) red[wv] = m;
  __syncthreads();
  float mm = red[0];
#pragma unroll
  for (int i = 1; i < 16; ++i) mm = fmaxf(mm, red[i]);
  float e0 = expf(v.x - mm), e1 = expf(v.y - mm), e2 = expf(v.z - mm), e3 = expf(v.w - mm);
  float s = wred_sum(e0 + e1 + e2 + e3);
  if (lane == 0) red2[wv] = s;
  __syncthreads();
  float tot = 0.f;
#pragma unroll
  for (int i = 0; i < 16; ++i) tot += red2[i];
  float inv = 1.f / tot;
  float4 o = {e0 * inv, e1 * inv, e2 * inv, e3 * inv};
  ((float4*)(w + (size_t)l * 4096))[t] = o;
}

// ---------- ctx: all 6 layers per block, 32 rows/chunk ----------
__global__ void ctx_k(const unsigned short* __restrict__ e, const float* __restrict__ w,
                      float* __restrict__ ctx) {
  int c = blockIdx.x, b = blockIdx.y, t = threadIdx.x;
  const unsigned short* eb = e + ((size_t)b * 4096 + c * 32) * 256;
  const float* w0 = w + c * 32;
  float a[6] = {0.f, 0.f, 0.f, 0.f, 0.f, 0.f};
#pragma unroll 4
  for (int i = 0; i < 32; ++i) {
    float ev = bf2f(eb[(size_t)i * 256 + t]);
#pragma unroll
    for (int l = 0; l < 6; ++l) a[l] += w0[l * 4096 + i] * ev;
  }
#pragma unroll
  for (int l = 0; l < 6; ++l) atomicAdd(&ctx[(l * 4 + b) * 256 + t], a[l]);
}

// ---------- xacc[b][t] += sum_l sum_{d in chunk} ctx[l][b][d]*Wv[l][d][t] ----------
__global__ void proj_k(const float* __restrict__ ctx, const float* __restrict__ Wv,
                       float* __restrict__ xacc) {
  int c = blockIdx.x, l = blockIdx.y, t = threadIdx.x;
  const float* W = Wv + (size_t)l * 65536;
  float pa[4] = {0.f, 0.f, 0.f, 0.f};
#pragma unroll
  for (int i = 0; i < 16; ++i) {
    int d = c * 16 + i;
    float wv = W[d * 256 + t];  // coalesced
#pragma unroll
    for (int b = 0; b < 4; ++b) pa[b] += ctx[(l * 4 + b) * 256 + d] * wv;
  }
#pragma unroll
  for (int b = 0; b < 4; ++b) atomicAdd(&xacc[b * 256 + t], pa[b]);
}

// ---------- final: residual (e + PRE-MLP p0 + attn) + LN ----------
__global__ void final_k(const unsigned short* __restrict__ e, const unsigned short* __restrict__ p0b,
                        const float* __restrict__ xacc, const float* __restrict__ gout,
                        float* __restrict__ xln) {
  int b = blockIdx.x, t = threadIdx.x;
  // Reference: x = e + p0 (pre-MLP LN(wpe)) + sum_l attn_l. NOT the MLP'd p!
  float v = xacc[b * 256 + t] + bf2f(e[((size_t)(b * 4096 + 4095)) * 256 + t]) +
            bf2f(p0b[(size_t)4095 * 256 + t]);
  __shared__ float s4[4];
  float mean = bsum256(v, s4) * (1.f / 256.f);
  float d = v - mean;
  float var = bsum256(d * d, s4) * (1.f / 256.f);
  xln[b * 256 + t] = d * rsqrtf(var + LN_EPS) * gout[t];
}

// ---------- logits ----------
__global__ void logits_k(const float* __restrict__ wte, const float* __restrict__ ge,
                         const float* __restrict__ xln, float* __restrict__ out) {
  int wv = threadIdx.x >> 6, lane = threadIdx.x & 63;
  int v = blockIdx.x * 4 + wv;
  float4 x = ((const float4*)(wte + (size_t)v * 256))[lane];
  float mean = wred_sum(x.x + x.y + x.z + x.w) * (1.f / 256.f);
  float4 d = {x.x - mean, x.y - mean, x.z - mean, x.w - mean};
  float var = wred_sum(d.x * d.x + d.y * d.y + d.z * d.z + d.w * d.w) * (1.f / 256.f);
  float r = rsqrtf(var + LN_EPS);
  float4 gv = ((const float4*)ge)[lane];
  float4 ln = {d.x * r * gv.x, d.y * r * gv.y, d.z * r * gv.z, d.w * r * gv.w};
#pragma unroll
  for (int b = 0; b < 4; ++b) {
    float4 xv = ((const float4*)(xln + b * 256))[lane];
    float dot = wred_sum(ln.x * xv.x + ln.y * xv.y + ln.z * xv.z + ln.w * xv.w);
    if (lane == 0) out[b * 32000 + v] = dot;
  }
}

// ---------- workspace layout (float units, 16B aligned) ----------
#define O_E     ((size_t)0)         // bf16 16384*256 -> 2097152 fl
#define O_P0B   ((size_t)2097152)   // bf16 4096*256  -> 524288 fl
#define O_W1T   ((size_t)2621440)   // bf16 1024*256  -> 131072 fl
#define O_HB    ((size_t)2752512)   // bf16 4096*1024 -> 2097152 fl
#define O_CTX   ((size_t)4849664)   // f32 6144   (zero block start)
#define O_QALL  ((size_t)4855808)   // f32 1536
#define O_XACC  ((size_t)4857344)   // f32 1024
#define O_PLAST ((size_t)4858368)   // f32 256
#define O_KV    ((size_t)4858624)   // f32 1536
#define O_W2KV  ((size_t)4860160)   // f32 6144
#define O_SC    ((size_t)4866304)   // f32 24576
#define O_WSM   ((size_t)4890880)   // f32 24576
#define O_XLN   ((size_t)4915456)   // f32 1024

extern "C" void kernel_launch(void* const* d_in, const int* in_sizes, int n_in,
                              void* d_out, int out_size, void* d_ws, size_t ws_size,
                              hipStream_t stream) {
  const int*   tokens = (const int*)d_in[0];
  const float* wte    = (const float*)d_in[1];
  const float* wpe    = (const float*)d_in[2];
  const float* g_e    = (const float*)d_in[3];
  const float* g_p    = (const float*)d_in[4];
  const float* g_out  = (const float*)d_in[5];
  const float* ff_w1  = (const float*)d_in[6];
  const float* ff_w2  = (const float*)d_in[7];
  const float* Wq     = (const float*)d_in[8];
  const float* Wk     = (const float*)d_in[9];
  const float* Wv     = (const float*)d_in[10];
  float* out = (float*)d_out;
  float* ws = (float*)d_ws;

  unsigned short* e   = (unsigned short*)(ws + O_E);
  unsigned short* p0b = (unsigned short*)(ws + O_P0B);
  unsigned short* w1T = (unsigned short*)(ws + O_W1T);
  unsigned short* hB  = (unsigned short*)(ws + O_HB);
  float* ctx   = ws + O_CTX;
  float* qall  = ws + O_QALL;
  float* xacc  = ws + O_XACC;
  float* plast = ws + O_PLAST;
  float* kv    = ws + O_KV;
  float* w2kv  = ws + O_W2KV;
  float* sc    = ws + O_SC;
  float* wsm   = ws + O_WSM;
  float* xln   = ws + O_XLN;

  // 1. fused prep (LNs -> bf16, W1^T, zero ctx/qall/xacc/plast)
  prep_k<<<5185, 256, 0, stream>>>(wpe, wte, tokens, g_p, g_e, ff_w1,
                                   p0b, e, w1T, ctx);
  // 2. MLP1: h = gelu(p0 @ W1)  [4096x1024x256], 64x64 tiles -> 1024 blocks
  mfma_gemm<2><<<dim3(64, 16), 256, 0, stream>>>(
      (const __hip_bfloat16*)p0b, (const __hip_bfloat16*)w1T,
      (__hip_bfloat16*)hB, 4096, 1024, 256, 1);
  // 3. plast = p0[4095] + h[4095] @ W2 (split-k atomics) — post-MLP p for q
  plast_k<<<64, 256, 0, stream>>>(hB, p0b, ff_w2, plast);
  // 4. q[l] = plast @ Wq[l] (split-d atomics)
  q_k<<<dim3(16, 6), 256, 0, stream>>>(plast, Wq, qall);
  // 5. kv[l] = Wk[l] @ q[l]
  kv_k<<<dim3(64, 6), 256, 0, stream>>>(Wk, qall, kv);
  // 6. w2kv[l] = W2 @ kv[l]
  w2kv_k<<<dim3(256, 6), 256, 0, stream>>>(ff_w2, kv, w2kv);
  // 7. scores: sc[l][t] = (p0[t].kv[l] + h[t].w2kv[l])/16
  sc_k<<<256, 256, 0, stream>>>(p0b, hB, kv, w2kv, sc);
  // 8. softmax
  softmax_k<<<6, 1024, 0, stream>>>(sc, wsm);
  // 9. ctx accumulation
  ctx_k<<<dim3(128, 4), 256, 0, stream>>>(e, wsm, ctx);
  // 10. Wv projection (split-d atomics into xacc)
  proj_k<<<dim3(16, 6), 256, 0, stream>>>(ctx, Wv, xacc);
  // 11. residual (e + pre-MLP p0 + attn) + final LN
  final_k<<<4, 256, 0, stream>>>(e, p0b, xacc, g_out, xln);
  // 12. logits
  logits_k<<<8000, 256, 0, stream>>>(wte, g_e, xln, out);
}

// Round 8
// 155.266 us; speedup vs baseline: 1.2775x; 1.2775x over previous
//
#include <hip/hip_runtime.h>
#include <hip/hip_bf16.h>

#define LN_EPS 1e-5f

typedef __attribute__((ext_vector_type(8))) short s8v;
typedef __attribute__((ext_vector_type(4))) float f32x4;

// ---------- helpers ----------
__device__ __forceinline__ float wred_sum(float v) {
#pragma unroll
  for (int o = 32; o > 0; o >>= 1) v += __shfl_xor(v, o, 64);
  return v;
}
__device__ __forceinline__ float wred_max(float v) {
#pragma unroll
  for (int o = 32; o > 0; o >>= 1) v = fmaxf(v, __shfl_xor(v, o, 64));
  return v;
}
__device__ __forceinline__ float bsum256(float v, float* s4) {
  v = wred_sum(v);
  int lane = threadIdx.x & 63, w = threadIdx.x >> 6;
  __syncthreads();
  if (lane == 0) s4[w] = v;
  __syncthreads();
  return s4[0] + s4[1] + s4[2] + s4[3];
}
__device__ __forceinline__ float bf2f(unsigned short u) {
  union { unsigned int i; float f; } c;
  c.i = ((unsigned int)u) << 16;
  return c.f;
}
__device__ __forceinline__ unsigned short f2bf(float f) {
  __hip_bfloat16 h = (__hip_bfloat16)f;
  return *(unsigned short*)&h;
}
__device__ __forceinline__ float4 bf4(ushort4 u) {
  return (float4){bf2f(u.x), bf2f(u.y), bf2f(u.z), bf2f(u.w)};
}
__device__ __forceinline__ void async_cp16(const __hip_bfloat16* g, __hip_bfloat16* l) {
  __builtin_amdgcn_global_load_lds(
      (const __attribute__((address_space(1))) unsigned int*)g,
      (__attribute__((address_space(3))) unsigned int*)l, 16, 0, 0);
}

// ---------- fused prep: ln(wpe)->p0b, ln(wte[tokens])->e, W1^T, zero accs ----------
__global__ void prep_k(const float* __restrict__ wpe, const float* __restrict__ wte,
                       const int* __restrict__ tokens,
                       const float* __restrict__ g_p, const float* __restrict__ g_e,
                       const float* __restrict__ ff_w1,
                       unsigned short* __restrict__ p0b, unsigned short* __restrict__ e,
                       unsigned short* __restrict__ w1T, float* __restrict__ zeros) {
  __shared__ float lds[64][65];
  int bx = blockIdx.x, t = threadIdx.x;
  int w = t >> 6, lane = t & 63;

  if (bx < 5120) {  // layernorm roles, wave per row
    int row;
    const float* g;
    const float4* src;
    if (bx < 1024) {           // p0 = LN(wpe[:4096], g_p)
      row = bx * 4 + w;
      src = (const float4*)(wpe + (size_t)row * 256);
      g = g_p;
    } else {                   // e = LN(wte[tokens], g_e)
      row = (bx - 1024) * 4 + w;
      int tok = tokens[row];
      src = (const float4*)(wte + (size_t)tok * 256);
      g = g_e;
    }
    float4 v = src[lane];
    float mean = wred_sum(v.x + v.y + v.z + v.w) * (1.f / 256.f);
    float4 d = {v.x - mean, v.y - mean, v.z - mean, v.w - mean};
    float var = wred_sum(d.x * d.x + d.y * d.y + d.z * d.z + d.w * d.w) * (1.f / 256.f);
    float r = rsqrtf(var + LN_EPS);
    float4 gv = ((const float4*)g)[lane];
    ushort4 ob = {f2bf(d.x * r * gv.x), f2bf(d.y * r * gv.y),
                  f2bf(d.z * r * gv.z), f2bf(d.w * r * gv.w)};
    if (bx < 1024) ((ushort4*)(p0b + (size_t)row * 256))[lane] = ob;
    else           ((ushort4*)(e   + (size_t)row * 256))[lane] = ob;
    return;
  }
  if (bx < 5184) {  // transpose-cast W1 (256x1024) -> w1T (1024x256)
    int i = bx - 5120;
    int bxx = i & 3, byy = i >> 2;   // 4 x 16 tiles of 64x64
    int x = t & 63, y4 = t >> 6;
    int r0 = bxx * 64, c0 = byy * 64;
#pragma unroll
    for (int k = 0; k < 16; ++k) {
      int r = y4 * 16 + k;
      lds[r][x] = ff_w1[(size_t)(r0 + r) * 1024 + c0 + x];
    }
    __syncthreads();
#pragma unroll
    for (int k = 0; k < 16; ++k) {
      int a = y4 * 16 + k;
      w1T[(size_t)(c0 + a) * 256 + r0 + x] = f2bf(lds[x][a]);
    }
    return;
  }
  // bx == 5184: zero accumulators (ctx 6144 + qall 1536 + xacc 1024 + plast 256)
  for (int i = t; i < 8960; i += 256) zeros[i] = 0.f;
}

// ---------- MFMA GEMM: C(MxN) = A(MxK) @ BT(NxK), 64x64 tile, BK=64 ----------
// mode 1: exact gelu epilogue. async global->LDS, XOR-swizzled chunks.
template <int TM>
__global__ __launch_bounds__(256, 4) void mfma_gemm(
    const __hip_bfloat16* __restrict__ A, const __hip_bfloat16* __restrict__ BT,
    __hip_bfloat16* __restrict__ Cout, int M, int N, int K, int mode) {
  constexpr int BM = TM * 32;
  __shared__ __hip_bfloat16 As[BM * 64];
  __shared__ __hip_bfloat16 Bs[64 * 64];
  const int t = threadIdx.x;
  const int lane = t & 63, wave = t >> 6;
  const int wr = wave >> 1, wc = wave & 1;
  const int fr = lane & 15, quad = lane >> 4;
  const int m0 = blockIdx.x * BM, n0 = blockIdx.y * 64;

  f32x4 acc[TM][2];
#pragma unroll
  for (int i = 0; i < TM; ++i)
#pragma unroll
    for (int j = 0; j < 2; ++j) acc[i][j] = (f32x4){0.f, 0.f, 0.f, 0.f};

  for (int k0 = 0; k0 < K; k0 += 64) {
    __syncthreads();
#pragma unroll
    for (int j = 0; j < TM; ++j) {
      int ld = wave * TM + j;
      int slot = ld * 64 + lane;
      int m = slot >> 3, c = slot & 7;
      const __hip_bfloat16* g = A + (size_t)(m0 + m) * K + k0 + ((c ^ (m & 7)) << 3);
      async_cp16(g, As + ld * 512);
    }
#pragma unroll
    for (int j = 0; j < 2; ++j) {
      int ld = wave * 2 + j;
      int slot = ld * 64 + lane;
      int n = slot >> 3, c = slot & 7;
      const __hip_bfloat16* g = BT + (size_t)(n0 + n) * K + k0 + ((c ^ (n & 7)) << 3);
      async_cp16(g, Bs + ld * 512);
    }
    __syncthreads();
#pragma unroll
    for (int h = 0; h < 2; ++h) {
      s8v af[TM], bfv[2];
#pragma unroll
      for (int i = 0; i < TM; ++i) {
        int m = wr * TM * 16 + i * 16 + fr;
        int ch = (h * 4 + quad) ^ (m & 7);
        af[i] = *(const s8v*)(As + m * 64 + ch * 8);
      }
#pragma unroll
      for (int j = 0; j < 2; ++j) {
        int n = wc * 32 + j * 16 + fr;
        int ch = (h * 4 + quad) ^ (n & 7);
        bfv[j] = *(const s8v*)(Bs + n * 64 + ch * 8);
      }
#pragma unroll
      for (int i = 0; i < TM; ++i)
#pragma unroll
        for (int j = 0; j < 2; ++j)
          acc[i][j] = __builtin_amdgcn_mfma_f32_16x16x32_bf16(af[i], bfv[j], acc[i][j], 0, 0, 0);
    }
  }

#pragma unroll
  for (int i = 0; i < TM; ++i) {
#pragma unroll
    for (int j = 0; j < 2; ++j) {
#pragma unroll
      for (int r = 0; r < 4; ++r) {
        int row = m0 + wr * TM * 16 + i * 16 + quad * 4 + r;
        int col = n0 + wc * 32 + j * 16 + fr;
        float v = acc[i][j][r];
        if (mode == 1) v = 0.5f * v * (1.f + erff(v * 0.70710678118654752f));
        Cout[(size_t)row * N + col] = (__hip_bfloat16)v;
      }
    }
  }
}

// ---------- plast[t] = p0b[4095][t] + sum_k h[4095][k]*W2[k][t]  (split-k atomics) ----------
__global__ void plast_k(const unsigned short* __restrict__ hB,
                        const unsigned short* __restrict__ p0b,
                        const float* __restrict__ W2, float* __restrict__ plast) {
  int c = blockIdx.x, t = threadIdx.x;
  float pa = (c == 0) ? bf2f(p0b[(size_t)4095 * 256 + t]) : 0.f;
#pragma unroll
  for (int i = 0; i < 16; ++i) {
    int k = c * 16 + i;
    pa += bf2f(hB[(size_t)4095 * 1024 + k]) * W2[(size_t)k * 256 + t];  // coalesced over t
  }
  atomicAdd(&plast[t], pa);
}

// ---------- q[l][t] += sum_{d in chunk} plast[d]*Wq[l][d][t] ----------
__global__ void q_k(const float* __restrict__ plast, const float* __restrict__ Wq,
                    float* __restrict__ qall) {
  int c = blockIdx.x, l = blockIdx.y, t = threadIdx.x;
  const float* W = Wq + (size_t)l * 65536;
  float pa = 0.f;
#pragma unroll
  for (int i = 0; i < 16; ++i) {
    int d = c * 16 + i;
    pa += plast[d] * W[d * 256 + t];  // coalesced over t
  }
  atomicAdd(&qall[l * 256 + t], pa);
}

// ---------- kv[l][r] = Wk[l][r] . q[l]  (wave per row) ----------
__global__ void kv_k(const float* __restrict__ Wk, const float* __restrict__ qall,
                     float* __restrict__ kv) {
  int l = blockIdx.y;
  int w = threadIdx.x >> 6, lane = threadIdx.x & 63;
  int r = blockIdx.x * 4 + w;
  float4 wv = ((const float4*)(Wk + (size_t)l * 65536 + (size_t)r * 256))[lane];
  float4 qv = ((const float4*)(qall + l * 256))[lane];
  float dot = wred_sum(wv.x * qv.x + wv.y * qv.y + wv.z * qv.z + wv.w * qv.w);
  if (lane == 0) kv[l * 256 + r] = dot;
}

// ---------- w2kv[l][r] = W2[r] . kv[l]  (wave per row, r<1024) ----------
__global__ void w2kv_k(const float* __restrict__ W2, const float* __restrict__ kv,
                       float* __restrict__ w2kv) {
  int l = blockIdx.y;
  int w = threadIdx.x >> 6, lane = threadIdx.x & 63;
  int r = blockIdx.x * 4 + w;
  float4 wv = ((const float4*)(W2 + (size_t)r * 256))[lane];
  float4 qv = ((const float4*)(kv + l * 256))[lane];
  float dot = wred_sum(wv.x * qv.x + wv.y * qv.y + wv.z * qv.z + wv.w * qv.w);
  if (lane == 0) w2kv[l * 1024 + r] = dot;
}

// ---------- sc[l][t] = (p0b[t].kv[l] + h[t].w2kv[l]) / 16 ----------
// 512 blocks x 4 waves x 2 rows sequential: small live set, no spills.
__global__ __launch_bounds__(256) void sc_k(
    const unsigned short* __restrict__ p0b, const unsigned short* __restrict__ hB,
    const float* __restrict__ kv, const float* __restrict__ w2kv,
    float* __restrict__ sc) {
  __shared__ float skv[6 * 256];
  __shared__ float sw2[6 * 1024];
  int t = threadIdx.x;
  for (int i = t; i < 1536; i += 256) skv[i] = kv[i];
  for (int i = t; i < 6144; i += 256) sw2[i] = w2kv[i];
  __syncthreads();
  int wave = t >> 6, lane = t & 63;
#pragma unroll
  for (int rr = 0; rr < 2; ++rr) {
    int row = blockIdx.x * 8 + wave * 2 + rr;
    const ushort4* hrow = (const ushort4*)(hB + (size_t)row * 1024);
    float4 h0 = bf4(hrow[lane]);
    float4 h1 = bf4(hrow[64 + lane]);
    float4 h2 = bf4(hrow[128 + lane]);
    float4 h3 = bf4(hrow[192 + lane]);
    float4 p = bf4(((const ushort4*)(p0b + (size_t)row * 256))[lane]);
#pragma unroll
    for (int l = 0; l < 6; ++l) {
      float4 kf = ((const float4*)(skv + l * 256))[lane];
      float4 w0 = ((const float4*)(sw2 + l * 1024))[lane];
      float4 w1 = ((const float4*)(sw2 + l * 1024 + 256))[lane];
      float4 w2 = ((const float4*)(sw2 + l * 1024 + 512))[lane];
      float4 w3 = ((const float4*)(sw2 + l * 1024 + 768))[lane];
      float a = p.x * kf.x + p.y * kf.y + p.z * kf.z + p.w * kf.w;
      a += h0.x * w0.x + h0.y * w0.y + h0.z * w0.z + h0.w * w0.w;
      a += h1.x * w1.x + h1.y * w1.y + h1.z * w1.z + h1.w * w1.w;
      a += h2.x * w2.x + h2.y * w2.y + h2.z * w2.z + h2.w * w2.w;
      a += h3.x * w3.x + h3.y * w3.y + h3.z * w3.z + h3.w * w3.w;
      a = wred_sum(a);
      if (lane == 0) sc[(size_t)l * 4096 + row] = a * 0.0625f;
    }
  }
}

// ---------- softmax over 4096 per layer ----------
__global__ void softmax_k(const float* __restrict__ sc, float* __restrict__ w) {
  int l = blockIdx.x, t = threadIdx.x;  // 1024 threads
  float4 v = ((const float4*)(sc + (size_t)l * 4096))[t];
  float m = fmaxf(fmaxf(v.x, v.y), fmaxf(v.z, v.w));
  m = wred_max(m);
  __shared__ float red[16];
  __shared__ float red2[16];
  int lane = t & 63, wv = t >> 6;
  if (lane == 0) red[wv] = m;
  __syncthreads();
  float mm = red[0];
#pragma unroll
  for (int i = 1; i < 16; ++i) mm = fmaxf(mm, red[i]);
  float e0 = expf(v.x - mm), e1 = expf(v.y - mm), e2 = expf(v.z - mm), e3 = expf(v.w - mm);
  float s = wred_sum(e0 + e1 + e2 + e3);
  if (lane == 0) red2[wv] = s;
  __syncthreads();
  float tot = 0.f;
#pragma unroll
  for (int i = 0; i < 16; ++i) tot += red2[i];
  float inv = 1.f / tot;
  float4 o = {e0 * inv, e1 * inv, e2 * inv, e3 * inv};
  ((float4*)(w + (size_t)l * 4096))[t] = o;
}

// ---------- ctx: all 6 layers per block, 32 rows/chunk ----------
__global__ void ctx_k(const unsigned short* __restrict__ e, const float* __restrict__ w,
                      float* __restrict__ ctx) {
  int c = blockIdx.x, b = blockIdx.y, t = threadIdx.x;
  const unsigned short* eb = e + ((size_t)b * 4096 + c * 32) * 256;
  const float* w0 = w + c * 32;
  float a[6] = {0.f, 0.f, 0.f, 0.f, 0.f, 0.f};
#pragma unroll 4
  for (int i = 0; i < 32; ++i) {
    float ev = bf2f(eb[(size_t)i * 256 + t]);
#pragma unroll
    for (int l = 0; l < 6; ++l) a[l] += w0[l * 4096 + i] * ev;
  }
#pragma unroll
  for (int l = 0; l < 6; ++l) atomicAdd(&ctx[(l * 4 + b) * 256 + t], a[l]);
}

// ---------- xacc[b][t] += sum_l sum_{d in chunk} ctx[l][b][d]*Wv[l][d][t] ----------
__global__ void proj_k(const float* __restrict__ ctx, const float* __restrict__ Wv,
                       float* __restrict__ xacc) {
  int c = blockIdx.x, l = blockIdx.y, t = threadIdx.x;
  const float* W = Wv + (size_t)l * 65536;
  float pa[4] = {0.f, 0.f, 0.f, 0.f};
#pragma unroll
  for (int i = 0; i < 16; ++i) {
    int d = c * 16 + i;
    float wv = W[d * 256 + t];  // coalesced
#pragma unroll
    for (int b = 0; b < 4; ++b) pa[b] += ctx[(l * 4 + b) * 256 + d] * wv;
  }
#pragma unroll
  for (int b = 0; b < 4; ++b) atomicAdd(&xacc[b * 256 + t], pa[b]);
}

// ---------- final: residual (e + PRE-MLP p0 + attn) + LN ----------
__global__ void final_k(const unsigned short* __restrict__ e, const unsigned short* __restrict__ p0b,
                        const float* __restrict__ xacc, const float* __restrict__ gout,
                        float* __restrict__ xln) {
  int b = blockIdx.x, t = threadIdx.x;
  float v = xacc[b * 256 + t] + bf2f(e[((size_t)(b * 4096 + 4095)) * 256 + t]) +
            bf2f(p0b[(size_t)4095 * 256 + t]);
  __shared__ float s4[4];
  float mean = bsum256(v, s4) * (1.f / 256.f);
  float d = v - mean;
  float var = bsum256(d * d, s4) * (1.f / 256.f);
  xln[b * 256 + t] = d * rsqrtf(var + LN_EPS) * gout[t];
}

// ---------- logits ----------
__global__ void logits_k(const float* __restrict__ wte, const float* __restrict__ ge,
                         const float* __restrict__ xln, float* __restrict__ out) {
  int wv = threadIdx.x >> 6, lane = threadIdx.x & 63;
  int v = blockIdx.x * 4 + wv;
  float4 x = ((const float4*)(wte + (size_t)v * 256))[lane];
  float mean = wred_sum(x.x + x.y + x.z + x.w) * (1.f / 256.f);
  float4 d = {x.x - mean, x.y - mean, x.z - mean, x.w - mean};
  float var = wred_sum(d.x * d.x + d.y * d.y + d.z * d.z + d.w * d.w) * (1.f / 256.f);
  float r = rsqrtf(var + LN_EPS);
  float4 gv = ((const float4*)ge)[lane];
  float4 ln = {d.x * r * gv.x, d.y * r * gv.y, d.z * r * gv.z, d.w * r * gv.w};
#pragma unroll
  for (int b = 0; b < 4; ++b) {
    float4 xv = ((const float4*)(xln + b * 256))[lane];
    float dot = wred_sum(ln.x * xv.x + ln.y * xv.y + ln.z * xv.z + ln.w * xv.w);
    if (lane == 0) out[b * 32000 + v] = dot;
  }
}

// ---------- workspace layout (float units, 16B aligned) ----------
#define O_E     ((size_t)0)         // bf16 16384*256 -> 2097152 fl
#define O_P0B   ((size_t)2097152)   // bf16 4096*256  -> 524288 fl
#define O_W1T   ((size_t)2621440)   // bf16 1024*256  -> 131072 fl
#define O_HB    ((size_t)2752512)   // bf16 4096*1024 -> 2097152 fl
#define O_CTX   ((size_t)4849664)   // f32 6144   (zero block start)
#define O_QALL  ((size_t)4855808)   // f32 1536
#define O_XACC  ((size_t)4857344)   // f32 1024
#define O_PLAST ((size_t)4858368)   // f32 256
#define O_KV    ((size_t)4858624)   // f32 1536
#define O_W2KV  ((size_t)4860160)   // f32 6144
#define O_SC    ((size_t)4866304)   // f32 24576
#define O_WSM   ((size_t)4890880)   // f32 24576
#define O_XLN   ((size_t)4915456)   // f32 1024

extern "C" void kernel_launch(void* const* d_in, const int* in_sizes, int n_in,
                              void* d_out, int out_size, void* d_ws, size_t ws_size,
                              hipStream_t stream) {
  const int*   tokens = (const int*)d_in[0];
  const float* wte    = (const float*)d_in[1];
  const float* wpe    = (const float*)d_in[2];
  const float* g_e    = (const float*)d_in[3];
  const float* g_p    = (const float*)d_in[4];
  const float* g_out  = (const float*)d_in[5];
  const float* ff_w1  = (const float*)d_in[6];
  const float* ff_w2  = (const float*)d_in[7];
  const float* Wq     = (const float*)d_in[8];
  const float* Wk     = (const float*)d_in[9];
  const float* Wv     = (const float*)d_in[10];
  float* out = (float*)d_out;
  float* ws = (float*)d_ws;

  unsigned short* e   = (unsigned short*)(ws + O_E);
  unsigned short* p0b = (unsigned short*)(ws + O_P0B);
  unsigned short* w1T = (unsigned short*)(ws + O_W1T);
  unsigned short* hB  = (unsigned short*)(ws + O_HB);
  float* ctx   = ws + O_CTX;
  float* qall  = ws + O_QALL;
  float* xacc  = ws + O_XACC;
  float* plast = ws + O_PLAST;
  float* kv    = ws + O_KV;
  float* w2kv  = ws + O_W2KV;
  float* sc    = ws + O_SC;
  float* wsm   = ws + O_WSM;
  float* xln   = ws + O_XLN;

  // 1. fused prep (LNs -> bf16, W1^T, zero ctx/qall/xacc/plast)
  prep_k<<<5185, 256, 0, stream>>>(wpe, wte, tokens, g_p, g_e, ff_w1,
                                   p0b, e, w1T, ctx);
  // 2. MLP1: h = gelu(p0 @ W1)  [4096x1024x256], 64x64 tiles -> 1024 blocks
  mfma_gemm<2><<<dim3(64, 16), 256, 0, stream>>>(
      (const __hip_bfloat16*)p0b, (const __hip_bfloat16*)w1T,
      (__hip_bfloat16*)hB, 4096, 1024, 256, 1);
  // 3. plast = p0[4095] + h[4095] @ W2 (split-k atomics) — post-MLP p for q only
  plast_k<<<64, 256, 0, stream>>>(hB, p0b, ff_w2, plast);
  // 4. q[l] = plast @ Wq[l] (split-d atomics)
  q_k<<<dim3(16, 6), 256, 0, stream>>>(plast, Wq, qall);
  // 5. kv[l] = Wk[l] @ q[l]
  kv_k<<<dim3(64, 6), 256, 0, stream>>>(Wk, qall, kv);
  // 6. w2kv[l] = W2 @ kv[l]
  w2kv_k<<<dim3(256, 6), 256, 0, stream>>>(ff_w2, kv, w2kv);
  // 7. scores: sc[l][t] = (p0[t].kv[l] + h[t].w2kv[l])/16
  sc_k<<<512, 256, 0, stream>>>(p0b, hB, kv, w2kv, sc);
  // 8. softmax
  softmax_k<<<6, 1024, 0, stream>>>(sc, wsm);
  // 9. ctx accumulation
  ctx_k<<<dim3(128, 4), 256, 0, stream>>>(e, wsm, ctx);
  // 10. Wv projection (split-d atomics into xacc)
  proj_k<<<dim3(16, 6), 256, 0, stream>>>(ctx, Wv, xacc);
  // 11. residual (e + pre-MLP p0 + attn) + final LN
  final_k<<<4, 256, 0, stream>>>(e, p0b, xacc, g_out, xln);
  // 12. logits
  logits_k<<<8000, 256, 0, stream>>>(wte, g_e, xln, out);
}